// Round 11
// baseline (1245.260 us; speedup 1.0000x reference)
//
#include <hip/hip_runtime.h>
#include <cstddef>

#define H 128

typedef unsigned short ushort_t;
typedef unsigned char uchar_t;
typedef __attribute__((ext_vector_type(8))) short short8;
typedef __attribute__((ext_vector_type(4))) float floatx4;
typedef __attribute__((ext_vector_type(2))) float floatx2;

// ---------------- helpers ----------------
__device__ __forceinline__ unsigned fkey(float f){
    unsigned u = __float_as_uint(f);
    return (u & 0x80000000u) ? ~u : (u | 0x80000000u);
}
__device__ __forceinline__ float funkey(unsigned k){
    unsigned u = (k & 0x80000000u) ? (k ^ 0x80000000u) : ~k;
    return __uint_as_float(u);
}
__device__ __forceinline__ ushort_t f2bf(float f){
    unsigned u = __float_as_uint(f);
    u += 0x7fffu + ((u >> 16) & 1u);      // round-to-nearest-even
    return (ushort_t)(u >> 16);
}
__device__ __forceinline__ float bf2f(ushort_t h){
    return __uint_as_float(((unsigned)h) << 16);
}
__device__ __forceinline__ uchar_t f2fp8(float v){
    int p = __builtin_amdgcn_cvt_pk_fp8_f32(v, v, 0, false);
    return (uchar_t)(p & 0xff);
}

// ---------------- embeddings (write bf16 states) ----------------
__global__ __launch_bounds__(256) void k_embed_place(
    const float* __restrict__ pf, const float* __restrict__ Wpe,
    const float* __restrict__ bpe, ushort_t* __restrict__ out, int P)
{
    int idx = blockIdx.x*256 + threadIdx.x;     // 4-elem group index over P*32
    if (idx >= P*32) return;
    int p = idx >> 5, q = (idx & 31) << 2;
    float v = pf[p];
    float4 w = *(const float4*)(Wpe + q);
    float4 b = *(const float4*)(bpe + q);
    ushort4 o;
    o.x = f2bf(v*w.x + b.x); o.y = f2bf(v*w.y + b.y);
    o.z = f2bf(v*w.z + b.z); o.w = f2bf(v*w.w + b.w);
    *(ushort4*)(out + (size_t)p*H + q) = o;
}

__global__ __launch_bounds__(256) void k_embed_trans(
    const float* __restrict__ tf, const float* __restrict__ Wte,
    const float* __restrict__ bte, ushort_t* __restrict__ out, int T)
{
    __shared__ float Wl[8*H];
    __shared__ float Bl[H];
    int tid = threadIdx.x;
    #pragma unroll
    for (int t = 0; t < 4; t++) Wl[tid + t*256] = Wte[tid + t*256];
    if (tid < H) Bl[tid] = bte[tid];
    __syncthreads();
    int idx = blockIdx.x*256 + tid;
    if (idx >= T*32) return;
    int t = idx >> 5, q = (idx & 31) << 2;
    float4 acc = *(float4*)(&Bl[q]);
    #pragma unroll
    for (int k = 0; k < 8; k++){
        float s = tf[(size_t)t*8 + k];
        float4 w = *(float4*)(&Wl[k*H + q]);
        acc.x += s*w.x; acc.y += s*w.y; acc.z += s*w.z; acc.w += s*w.w;
    }
    ushort4 o;
    o.x = f2bf(acc.x); o.y = f2bf(acc.y); o.z = f2bf(acc.z); o.w = f2bf(acc.w);
    *(ushort4*)(out + (size_t)t*H + q) = o;
}

// prefix embedding + zero small accumulators + all softmax slots
__global__ void k_init_small(const float* __restrict__ pe, int plen,
                             const float* __restrict__ Wpr, const float* __restrict__ bpr,
                             float* __restrict__ prefix, float* __restrict__ meanP,
                             float* __restrict__ meanT, float* __restrict__ slots)
{
    int c = threadIdx.x;  // 128 threads
    float a = bpr[c];
    for (int k = 0; k < plen; k++) a += pe[k]*Wpr[k*H + c];
    prefix[c] = a;
    meanP[c] = 0.f;
    meanT[c] = 0.f;
    if (c < 16) slots[c] = 0.f;   // fkey-space 0 == -inf; Sp slots start at 0
}

// ---------------- weight transpose + bf16 convert ----------------
// per layer l: WT layout [p2tT 128x128][t2pT 128x128][tuT 128x256][puT 128x256]
__global__ __launch_bounds__(256) void k_wconv(
    const float* __restrict__ p2t_W, const float* __restrict__ t2p_W,
    const float* __restrict__ tu_W,  const float* __restrict__ pu_W,
    ushort_t* __restrict__ WT, int total)
{
    int e = blockIdx.x*256 + threadIdx.x;
    if (e >= total) return;
    int l = e / 98304, o = e - l*98304;
    const float* src; int K, oo;
    if (o < 16384)      { src = p2t_W + (size_t)l*16384; K = 128; oo = o; }
    else if (o < 32768) { src = t2p_W + (size_t)l*16384; K = 128; oo = o - 16384; }
    else if (o < 65536) { src = tu_W  + (size_t)l*32768; K = 256; oo = o - 32768; }
    else                { src = pu_W  + (size_t)l*32768; K = 256; oo = o - 65536; }
    int n = oo / K, k = oo - n*K;
    WT[e] = f2bf(src[(size_t)k*H + n]);
}

// ---------------- CSR build ----------------
__global__ __launch_bounds__(256) void k_zero_ints(int* __restrict__ p, int n)
{
    int i = blockIdx.x*256 + threadIdx.x;
    int stride = gridDim.x*256;
    for (; i < n; i += stride) p[i] = 0;
}

// dst histograms + per-edge segment ranks (2 atomics/edge; deg removed —
// softmax denominator is now accumulated inside k_gather)
__global__ __launch_bounds__(256) void k_hist2(
    const int* __restrict__ preD, const int* __restrict__ postD, int E,
    int* __restrict__ cntPre, int* __restrict__ cntPost,
    int* __restrict__ rankPre, int* __restrict__ rankPost)
{
    int i = blockIdx.x*256 + threadIdx.x;
    int stride = gridDim.x*256;
    for (; i < E; i += stride){
        rankPre[i] = atomicAdd(&cntPre[preD[i]], 1);
        rankPost[i] = atomicAdd(&cntPost[postD[i]], 1);
    }
}

// ---- multi-block exclusive scan (chunk = 1024 per block) ----
__global__ __launch_bounds__(256) void k_scan_part(
    const int* __restrict__ cnt, int N, int* __restrict__ bsum)
{
    __shared__ int wsum[4];
    int tid = threadIdx.x, lane = tid & 63, wid = tid >> 6;
    int base = blockIdx.x*1024 + tid*4;
    int4 v = make_int4(0,0,0,0);
    if (base + 3 < N) v = *(const int4*)(cnt + base);
    else {
        if (base+0 < N) v.x = cnt[base+0];
        if (base+1 < N) v.y = cnt[base+1];
        if (base+2 < N) v.z = cnt[base+2];
    }
    int s = v.x + v.y + v.z + v.w;
    #pragma unroll
    for (int o = 1; o < 64; o <<= 1) s += __shfl_xor(s, o);
    if (lane == 0) wsum[wid] = s;
    __syncthreads();
    if (tid == 0) bsum[blockIdx.x] = wsum[0] + wsum[1] + wsum[2] + wsum[3];
}

__global__ __launch_bounds__(256) void k_scan_bsum(int* __restrict__ bsum, int nb)
{
    __shared__ int wsum[4];
    int tid = threadIdx.x, lane = tid & 63, wid = tid >> 6;
    int x = (tid < nb) ? bsum[tid] : 0;
    int inc = x;
    #pragma unroll
    for (int o = 1; o < 64; o <<= 1){
        int u = __shfl_up(inc, o);
        if (lane >= o) inc += u;
    }
    if (lane == 63) wsum[wid] = inc;
    __syncthreads();
    int woff = 0;
    if (wid > 0) woff += wsum[0];
    if (wid > 1) woff += wsum[1];
    if (wid > 2) woff += wsum[2];
    if (tid < nb) bsum[tid] = woff + inc - x;
}

__global__ __launch_bounds__(256) void k_scan_final(
    const int* __restrict__ cnt, int N, const int* __restrict__ bsum,
    int* __restrict__ rp, int E)
{
    __shared__ int wsum[4];
    int tid = threadIdx.x, lane = tid & 63, wid = tid >> 6;
    int base = blockIdx.x*1024 + tid*4;
    int4 v = make_int4(0,0,0,0);
    if (base + 3 < N) v = *(const int4*)(cnt + base);
    else {
        if (base+0 < N) v.x = cnt[base+0];
        if (base+1 < N) v.y = cnt[base+1];
        if (base+2 < N) v.z = cnt[base+2];
    }
    int t0 = v.x, t1 = t0 + v.y, t2 = t1 + v.z, t3 = t2 + v.w;
    int inc = t3;
    #pragma unroll
    for (int o = 1; o < 64; o <<= 1){
        int u = __shfl_up(inc, o);
        if (lane >= o) inc += u;
    }
    if (lane == 63) wsum[wid] = inc;
    __syncthreads();
    int woff = 0;
    if (wid > 0) woff += wsum[0];
    if (wid > 1) woff += wsum[1];
    if (wid > 2) woff += wsum[2];
    int off = bsum[blockIdx.x] + woff + inc - t3;
    if (base+0 < N) rp[base+0] = off;
    if (base+1 < N) rp[base+1] = off + t0;
    if (base+2 < N) rp[base+2] = off + t1;
    if (base+3 < N) rp[base+3] = off + t2;
    if (blockIdx.x == 0 && tid == 0) rp[N] = E;
}

// atomic-free CSR fill using precomputed ranks
__global__ __launch_bounds__(256) void k_fill2(
    const int* __restrict__ preS, const int* __restrict__ preD,
    const int* __restrict__ postS, const int* __restrict__ postD, int E,
    const int* __restrict__ rpPre, const int* __restrict__ rankPre, int* __restrict__ csrPre,
    const int* __restrict__ rpPost, const int* __restrict__ rankPost, int* __restrict__ csrPost)
{
    int i = blockIdx.x*256 + threadIdx.x;
    int stride = gridDim.x*256;
    for (; i < E; i += stride){
        csrPre[rpPre[preD[i]] + rankPre[i]] = preS[i];
        csrPost[rpPost[postD[i]] + rankPost[i]] = postS[i];
    }
}

// ---------------- message GEMM: out(fp8) = A @ W + b, partial score (K=128) --
// W strips in REGISTERS (zero LDS). Block = 4 waves = 4 x 32-col strips =
// full 128-col rows per block. Barrier-free. Per-wave score partials -> y4.
__global__ __launch_bounds__(256, 4) void k_gemm_msg(
    const ushort_t* __restrict__ A, const ushort_t* __restrict__ WT,
    const float* __restrict__ bias, uchar_t* __restrict__ out, int M,
    const float* __restrict__ aw, float* __restrict__ y4)
{
    int tid = threadIdx.x;
    int lane = tid & 63, wid = tid >> 6;
    int quad = lane >> 4, l15 = lane & 15;
    int strip = wid*32;
    short8 bfr[2][4];
    float bcol[2], awc[2];
    #pragma unroll
    for (int j = 0; j < 2; j++){
        int col = strip + j*16 + l15;
        #pragma unroll
        for (int kk = 0; kk < 4; kk++)
            bfr[j][kk] = *(const short8*)(WT + (size_t)col*128 + kk*32 + quad*8);
        bcol[j] = bias[col];
        awc[j]  = aw[col];
    }
    int tiles = (M + 15) >> 4;
    for (int t = blockIdx.x; t < tiles; t += gridDim.x){
        int row0 = t << 4;
        int rA = row0 + l15; if (rA >= M) rA = M - 1;
        short8 afr[4];
        #pragma unroll
        for (int kk = 0; kk < 4; kk++)
            afr[kk] = *(const short8*)(A + (size_t)rA*H + kk*32 + quad*8);
        floatx4 acc[2];
        acc[0] = (floatx4)0.f; acc[1] = (floatx4)0.f;
        #pragma unroll
        for (int j = 0; j < 2; j++)
            #pragma unroll
            for (int kk = 0; kk < 4; kk++)
                acc[j] = __builtin_amdgcn_mfma_f32_16x16x32_bf16(afr[kk], bfr[j][kk], acc[j], 0,0,0);
        float pr[4] = {0.f,0.f,0.f,0.f};
        #pragma unroll
        for (int j = 0; j < 2; j++){
            int col = strip + j*16 + l15;
            #pragma unroll
            for (int rr = 0; rr < 4; rr++){
                int grow = row0 + quad*4 + rr;
                if (grow < M){
                    float v = acc[j][rr] + bcol[j];
                    out[(size_t)grow*H + col] = f2fp8(v);
                    pr[rr] += v * awc[j];
                }
            }
        }
        #pragma unroll
        for (int rr = 0; rr < 4; rr++){
            float p = pr[rr];
            p += __shfl_xor(p, 1); p += __shfl_xor(p, 2);
            p += __shfl_xor(p, 4); p += __shfl_xor(p, 8);
            int grow = row0 + quad*4 + rr;
            if (l15 == 0 && grow < M) y4[(size_t)grow*4 + wid] = p;
        }
    }
}

// ---------------- finalize scores: y = sum(y4) + ab; node max -> Mkey --------
__global__ __launch_bounds__(256) void k_scoremax(
    const float* __restrict__ y4, int N, const float* __restrict__ abp,
    float* __restrict__ y, unsigned* __restrict__ Mkey)
{
    __shared__ float wm[4];
    int tid = threadIdx.x;
    int lane = tid & 63, wid = tid >> 6;
    int gid = blockIdx.x*256 + tid, stride = gridDim.x*256;
    float ab = abp[0];
    float lmax = -3.402823466e38f;
    for (int r = gid; r < N; r += stride){
        float4 v = *(const float4*)(y4 + (size_t)r*4);
        float s = v.x + v.y + v.z + v.w + ab;
        y[r] = s;
        lmax = fmaxf(lmax, s);
    }
    #pragma unroll
    for (int o = 1; o < 64; o <<= 1) lmax = fmaxf(lmax, __shfl_xor(lmax, o));
    if (lane == 0) wm[wid] = lmax;
    __syncthreads();
    if (tid == 0){
        float m = fmaxf(fmaxf(wm[0], wm[1]), fmaxf(wm[2], wm[3]));
        atomicMax(Mkey, fkey(m));
    }
}

// ---------------- update GEMM: out = relu(A1 + A1@W_up + invS*(Mb@W_low) + b)
// W strips in REGISTERS, zero-LDS main loop, full 128-col rows per block.
// Dual accumulators: message half scaled by invS (softmax normalization moved
// here from the gather; GEMM is linear in Mb).
__global__ __launch_bounds__(256, 3) void k_gemm_up(
    const ushort_t* __restrict__ A1, const ushort_t* __restrict__ A2,
    const ushort_t* __restrict__ WT, const float* __restrict__ bias,
    const float* __restrict__ Sp, ushort_t* __restrict__ out, int M,
    float* __restrict__ colsum)
{
    __shared__ float csum[H];
    int tid = threadIdx.x;
    int lane = tid & 63, wid = tid >> 6;
    int quad = lane >> 4, l15 = lane & 15;
    int strip = wid*32;
    short8 bfr[2][8];
    float bcol[2];
    #pragma unroll
    for (int j = 0; j < 2; j++){
        int col = strip + j*16 + l15;
        #pragma unroll
        for (int kk = 0; kk < 8; kk++)
            bfr[j][kk] = *(const short8*)(WT + (size_t)col*256 + kk*32 + quad*8);
        bcol[j] = bias[col];
    }
    float invS = 1.f / Sp[0];
    const bool has_cs = (colsum != nullptr);
    if (has_cs && tid < H) csum[tid] = 0.f;
    float cs[2] = {0.f, 0.f};
    int tiles = (M + 15) >> 4;
    for (int t = blockIdx.x; t < tiles; t += gridDim.x){
        int row0 = t << 4;
        int rA = row0 + l15; if (rA >= M) rA = M - 1;
        short8 afr[8];
        #pragma unroll
        for (int kk = 0; kk < 4; kk++)
            afr[kk] = *(const short8*)(A1 + (size_t)rA*H + kk*32 + quad*8);
        #pragma unroll
        for (int kk = 0; kk < 4; kk++)
            afr[4+kk] = *(const short8*)(A2 + (size_t)rA*H + kk*32 + quad*8);
        floatx4 acc1[2], acc2[2];
        acc1[0] = (floatx4)0.f; acc1[1] = (floatx4)0.f;
        acc2[0] = (floatx4)0.f; acc2[1] = (floatx4)0.f;
        #pragma unroll
        for (int j = 0; j < 2; j++){
            #pragma unroll
            for (int kk = 0; kk < 4; kk++)
                acc1[j] = __builtin_amdgcn_mfma_f32_16x16x32_bf16(afr[kk], bfr[j][kk], acc1[j], 0,0,0);
            #pragma unroll
            for (int kk = 4; kk < 8; kk++)
                acc2[j] = __builtin_amdgcn_mfma_f32_16x16x32_bf16(afr[kk], bfr[j][kk], acc2[j], 0,0,0);
        }
        #pragma unroll
        for (int j = 0; j < 2; j++){
            int col = strip + j*16 + l15;
            #pragma unroll
            for (int rr = 0; rr < 4; rr++){
                int grow = row0 + quad*4 + rr;
                if (grow < M){
                    float v = acc1[j][rr] + invS*acc2[j][rr] + bcol[j]
                            + bf2f(A1[(size_t)grow*H + col]);
                    v = fmaxf(v, 0.f);
                    out[(size_t)grow*H + col] = f2bf(v);
                    if (has_cs) cs[j] += v;
                }
            }
        }
    }
    if (has_cs){
        #pragma unroll
        for (int j = 0; j < 2; j++){
            float v = cs[j];
            v += __shfl_xor(v, 16); v += __shfl_xor(v, 32);
            if (quad == 0) atomicAdd(&csum[strip + j*16 + l15], v);
        }
        __syncthreads();
        if (tid < H) atomicAdd(&colsum[tid], csum[tid]);
    }
}

// accumulate 8 fp8 (one int2) into 8 fp32 with weight
__device__ __forceinline__ void acc8f8(float* a, int2 u, float w){
    floatx2 p;
    p = __builtin_amdgcn_cvt_pk_f32_fp8(u.x, false); a[0] += w*p.x; a[1] += w*p.y;
    p = __builtin_amdgcn_cvt_pk_f32_fp8(u.x, true);  a[2] += w*p.x; a[3] += w*p.y;
    p = __builtin_amdgcn_cvt_pk_f32_fp8(u.y, false); a[4] += w*p.x; a[5] += w*p.y;
    p = __builtin_amdgcn_cvt_pk_f32_fp8(u.y, true);  a[6] += w*p.x; a[7] += w*p.y;
}

// ---------------- CSR gather: fp8 X rows -> UNNORMALIZED bf16 Mb -------------
// Also accumulates the softmax denominator S = sum_e exp(y[src]-M) (each edge
// visited exactly once across groups) -> one atomicAdd per block.
__global__ __launch_bounds__(256) void k_gather(
    const int* __restrict__ rp, const int* __restrict__ csr, int Nrow,
    const float* __restrict__ y, const uchar_t* __restrict__ X,
    ushort_t* __restrict__ Mb, const unsigned* __restrict__ Mkey,
    float* __restrict__ Sp)
{
    __shared__ float ssum;
    int tid = threadIdx.x;
    if (tid == 0) ssum = 0.f;
    __syncthreads();
    int g = tid >> 4, gl = tid & 15;          // 16 groups x 16 lanes
    int r = blockIdx.x*16 + g;
    float sloc = 0.f;
    if (r < Nrow){
        float Mv = funkey(Mkey[0]);
        int j0 = rp[r], j1 = rp[r+1];
        const int2* X8 = (const int2*)X;      // fp8 row = 16 int2 (128 fp8)
        float a[8] = {0.f,0.f,0.f,0.f,0.f,0.f,0.f,0.f};
        int j = j0;
        for (; j + 1 < j1; j += 2){
            int s0 = csr[j], s1 = csr[j+1];
            float e0 = expf(y[s0] - Mv);
            float e1 = expf(y[s1] - Mv);
            int2 u0 = X8[(size_t)s0*16 + gl];
            int2 u1 = X8[(size_t)s1*16 + gl];
            acc8f8(a, u0, e0);
            acc8f8(a, u1, e1);
            sloc += e0 + e1;
        }
        if (j < j1){
            int s0 = csr[j];
            float e0 = expf(y[s0] - Mv);
            int2 u0 = X8[(size_t)s0*16 + gl];
            acc8f8(a, u0, e0);
            sloc += e0;
        }
        int4 o;
        o.x = (int)((((unsigned)f2bf(a[1])) << 16) | (unsigned)f2bf(a[0]));
        o.y = (int)((((unsigned)f2bf(a[3])) << 16) | (unsigned)f2bf(a[2]));
        o.z = (int)((((unsigned)f2bf(a[5])) << 16) | (unsigned)f2bf(a[4]));
        o.w = (int)((((unsigned)f2bf(a[7])) << 16) | (unsigned)f2bf(a[6]));
        ((int4*)Mb)[(size_t)r*16 + gl] = o;
    }
    if (gl == 0) atomicAdd(&ssum, sloc);
    __syncthreads();
    if (tid == 0) atomicAdd(Sp, ssum);
}

// ---------------- tiny MLP head ----------------
__global__ __launch_bounds__(256) void k_head(
    const float* __restrict__ meanP, const float* __restrict__ meanT,
    float invP, float invT,
    const float* __restrict__ Wpp, const float* __restrict__ bpp,
    const float* __restrict__ Wtp, const float* __restrict__ btp,
    const float* __restrict__ prefix,
    const float* __restrict__ W1, const float* __restrict__ b1,
    const float* __restrict__ W2, const float* __restrict__ b2,
    float* __restrict__ h2g)
{
    __shared__ float comb[384];
    __shared__ float h1s[256];
    int tid = threadIdx.x;
    if (tid < 128){
        float a = bpp[tid];
        for (int k = 0; k < 128; k++) a += meanP[k]*invP*Wpp[k*H + tid];
        comb[tid] = a;
        comb[256 + tid] = prefix[tid];
    } else {
        int c = tid - 128;
        float a = btp[c];
        for (int k = 0; k < 128; k++) a += meanT[k]*invT*Wtp[k*H + c];
        comb[128 + c] = a;
    }
    __syncthreads();
    {
        float a = b1[tid];
        for (int k = 0; k < 384; k++) a += comb[k]*W1[k*256 + tid];
        h1s[tid] = fmaxf(a, 0.f);
    }
    __syncthreads();
    if (tid < 128){
        float a = b2[tid];
        for (int k = 0; k < 256; k++) a += h1s[k]*W2[k*H + tid];
        h2g[tid] = fmaxf(a, 0.f);
    }
}

// ---------------- logits + sigmoid ----------------
__global__ __launch_bounds__(256) void k_logits(
    const float* __restrict__ h2g, const float* __restrict__ W3,
    const float* __restrict__ b3, float* __restrict__ out, int T)
{
    __shared__ float h2l[128];
    int tid = threadIdx.x;
    if (tid < 128) h2l[tid] = h2g[tid];
    __syncthreads();
    int t = blockIdx.x*256 + tid;
    if (t >= T) return;
    float a = b3[t];
    #pragma unroll 8
    for (int k = 0; k < 128; k++) a += h2l[k]*W3[(size_t)k*T + t];
    out[t] = 1.f/(1.f + expf(-a));
}

// ---------------- launch ----------------
extern "C" void kernel_launch(void* const* d_in, const int* in_sizes, int n_in,
                              void* d_out, int out_size, void* d_ws, size_t ws_size,
                              hipStream_t stream)
{
    (void)n_in; (void)out_size; (void)ws_size;
    const float* pf    = (const float*)d_in[0];
    const float* tf    = (const float*)d_in[1];
    const float* pe    = (const float*)d_in[2];
    const int*   pre   = (const int*)d_in[3];
    const int*   post  = (const int*)d_in[4];
    const float* W_pe  = (const float*)d_in[5];
    const float* b_pe  = (const float*)d_in[6];
    const float* W_te  = (const float*)d_in[7];
    const float* b_te  = (const float*)d_in[8];
    const float* W_pr  = (const float*)d_in[9];
    const float* b_pr  = (const float*)d_in[10];
    const float* p2t_W = (const float*)d_in[11];
    const float* p2t_b = (const float*)d_in[12];
    const float* t2p_W = (const float*)d_in[13];
    const float* t2p_b = (const float*)d_in[14];
    const float* pu_W  = (const float*)d_in[15];
    const float* pu_b  = (const float*)d_in[16];
    const float* tu_W  = (const float*)d_in[17];
    const float* tu_b  = (const float*)d_in[18];
    const float* pa_W  = (const float*)d_in[19];
    const float* pa_b  = (const float*)d_in[20];
    const float* ta_W  = (const float*)d_in[21];
    const float* ta_b  = (const float*)d_in[22];
    const float* W_pp  = (const float*)d_in[23];
    const float* b_pp  = (const float*)d_in[24];
    const float* W_tp  = (const float*)d_in[25];
    const float* b_tp  = (const float*)d_in[26];
    const float* W1    = (const float*)d_in[27];
    const float* b1    = (const float*)d_in[28];
    const float* W2    = (const float*)d_in[29];
    const float* b2    = (const float*)d_in[30];
    const float* W3    = (const float*)d_in[31];
    const float* b3    = (const float*)d_in[32];

    int P = in_sizes[0];
    int T = in_sizes[1] / 8;
    int E = in_sizes[3] / 2;
    int plen = in_sizes[2];
    int L = in_sizes[11] / (H*H);

    float* ws = (float*)d_ws;
    size_t fP = (size_t)P*H, fT = (size_t)T*H;
    size_t fN = (fP > fT) ? fP : fT;
    int   Nmax = (P > T) ? P : T;

    float* yb = ws;                       // [Nmax] fp32 scores
    float* y4 = yb + Nmax;                // [Nmax*4] per-wave score partials
    float* sc = y4 + (size_t)Nmax*4;      // 16 softmax slots + small vectors
    float* meanP   = sc + 16;
    float* meanT   = sc + 144;
    float* prefix  = sc + 272;
    float* h2g     = sc + 400;            // end at sc+544 (16B aligned)

    ushort_t* bh = (ushort_t*)(sc + 544);
    ushort_t* place_h = bh;               // [P,128] bf16
    ushort_t* trans_h = place_h + fP;     // [T,128]
    ushort_t* Mb      = trans_h + fT;     // [Nmax,128] bf16 messages (unnormalized)
    ushort_t* Pb2     = Mb + fN;          // [P,128] ping-pong place
    ushort_t* Tb2     = Pb2 + fP;         // [T,128] ping-pong trans
    ushort_t* WTb     = Tb2 + fT;         // L*98304 bf16 transposed weights
    uchar_t*  Xf8     = (uchar_t*)(WTb + (size_t)L*98304);  // [Nmax,128] fp8 X

    int* iw = (int*)(Xf8 + fN);
    int* cntPre  = iw;                 // [T]
    int* cntPost = cntPre + T;         // [P]
    int* rpPre   = cntPost + P;        // [T+1]
    int* rpPost  = rpPre + (T + 1);    // [P+1]
    int* csrPre  = rpPost + (P + 2);   // [E]
    int* csrPost = csrPre + E;         // [E]
    int* rankPre = csrPost + E;        // [E]
    int* rankPost= rankPre + E;        // [E]
    int* bsumA   = rankPost + E;       // [256]
    int* bsumB   = bsumA + 256;        // [256]

    const int* pre_src  = pre;          const int* pre_dst  = pre + E;
    const int* post_src = post;         const int* post_dst = post + E;

    int wtot = L*98304;
    int nbT = (T + 1023)/1024, nbP = (P + 1023)/1024;

    k_init_small<<<1, 128, 0, stream>>>(pe, plen, W_pr, b_pr, prefix, meanP, meanT, sc);
    k_wconv<<<(wtot + 255)/256, 256, 0, stream>>>(p2t_W, t2p_W, tu_W, pu_W, WTb, wtot);
    k_zero_ints<<<256, 256, 0, stream>>>(iw, P + T);
    k_hist2<<<2048, 256, 0, stream>>>(pre_dst, post_dst, E,
                                      cntPre, cntPost, rankPre, rankPost);
    k_scan_part<<<nbT, 256, 0, stream>>>(cntPre, T, bsumA);
    k_scan_bsum<<<1, 256, 0, stream>>>(bsumA, nbT);
    k_scan_final<<<nbT, 256, 0, stream>>>(cntPre, T, bsumA, rpPre, E);
    k_scan_part<<<nbP, 256, 0, stream>>>(cntPost, P, bsumB);
    k_scan_bsum<<<1, 256, 0, stream>>>(bsumB, nbP);
    k_scan_final<<<nbP, 256, 0, stream>>>(cntPost, P, bsumB, rpPost, E);
    k_fill2<<<1024, 256, 0, stream>>>(pre_src, pre_dst, post_src, post_dst, E,
                                      rpPre, rankPre, csrPre,
                                      rpPost, rankPost, csrPost);

    k_embed_place<<<(P*32 + 255)/256, 256, 0, stream>>>(pf, W_pe, b_pe, place_h, P);
    k_embed_trans<<<(T*32 + 255)/256, 256, 0, stream>>>(tf, W_te, b_te, trans_h, T);

    ushort_t* curP = place_h; ushort_t* altP = Pb2;
    ushort_t* curT = trans_h; ushort_t* altT = Tb2;

    for (int l = 0; l < L; l++){
        const ushort_t* WTl  = WTb + (size_t)l*98304;
        const ushort_t* p2tT = WTl;
        const ushort_t* t2pT = WTl + 16384;
        const ushort_t* tuT  = WTl + 32768;
        const ushort_t* puT  = WTl + 65536;
        const float* p2tb = p2t_b + (size_t)l*H;
        const float* t2pb = t2p_b + (size_t)l*H;
        const float* pub  = pu_b  + (size_t)l*H;
        const float* tub  = tu_b  + (size_t)l*H;
        const float* paW  = pa_W + (size_t)l*H;   const float* pab = pa_b + l;
        const float* taW  = ta_W + (size_t)l*H;   const float* tab = ta_b + l;
        unsigned* MkA = (unsigned*)(sc + l*4 + 0);   float* SpA = sc + l*4 + 1;
        unsigned* MkB = (unsigned*)(sc + l*4 + 2);   float* SpB = sc + l*4 + 3;
        int last = (l == L-1);

        // phase A: place -> transition (partial scores fused)
        k_gemm_msg<<<1024, 256, 0, stream>>>(curP, p2tT, p2tb, Xf8, P, taW, y4);
        k_scoremax<<<128, 256, 0, stream>>>(y4, P, tab, yb, MkA);
        // gather writes unnormalized Mb and accumulates S_A into SpA
        k_gather<<<(T + 15)/16, 256, 0, stream>>>(rpPre, csrPre, T, yb, Xf8, Mb, MkA, SpA);

        // phase B: transform from OLD trans_h (+ its scores)
        k_gemm_msg<<<1024, 256, 0, stream>>>(curT, t2pT, t2pb, Xf8, T, paW, y4);
        k_scoremax<<<128, 256, 0, stream>>>(y4, T, pab, yb, MkB);

        // transition update (consumes Mb = trans_msg, normalized by 1/SpA)
        k_gemm_up<<<1024, 256, 0, stream>>>(curT, Mb, tuT, tub, SpA, altT, T,
                                            last ? meanT : nullptr);

        // place messages (S_B into SpB), then place update
        k_gather<<<(P + 15)/16, 256, 0, stream>>>(rpPost, csrPost, P, yb, Xf8, Mb, MkB, SpB);
        k_gemm_up<<<1024, 256, 0, stream>>>(curP, Mb, puT, pub, SpB, altP, P,
                                            last ? meanP : nullptr);

        ushort_t* tmp;
        tmp = curT; curT = altT; altT = tmp;
        tmp = curP; curP = altP; altP = tmp;
    }

    k_head<<<1, 256, 0, stream>>>(meanP, meanT, 1.f/(float)P, 1.f/(float)T,
                                  W_pp, b_pp, W_tp, b_tp, prefix, W1, b1, W2, b2, h2g);
    k_logits<<<(T + 255)/256, 256, 0, stream>>>(h2g, W3, b3, (float*)d_out, T);
}

// Round 12
// 884.412 us; speedup vs baseline: 1.4080x; 1.4080x over previous
//
#include <hip/hip_runtime.h>
#include <cstddef>

#define H 128

typedef unsigned short ushort_t;
typedef unsigned char uchar_t;
typedef __attribute__((ext_vector_type(8))) short short8;
typedef __attribute__((ext_vector_type(4))) float floatx4;
typedef __attribute__((ext_vector_type(2))) float floatx2;

// ---------------- helpers ----------------
__device__ __forceinline__ unsigned fkey(float f){
    unsigned u = __float_as_uint(f);
    return (u & 0x80000000u) ? ~u : (u | 0x80000000u);
}
__device__ __forceinline__ float funkey(unsigned k){
    unsigned u = (k & 0x80000000u) ? (k ^ 0x80000000u) : ~k;
    return __uint_as_float(u);
}
__device__ __forceinline__ ushort_t f2bf(float f){
    unsigned u = __float_as_uint(f);
    u += 0x7fffu + ((u >> 16) & 1u);      // round-to-nearest-even
    return (ushort_t)(u >> 16);
}
__device__ __forceinline__ float bf2f(ushort_t h){
    return __uint_as_float(((unsigned)h) << 16);
}
__device__ __forceinline__ uchar_t f2fp8(float v){
    int p = __builtin_amdgcn_cvt_pk_fp8_f32(v, v, 0, false);
    return (uchar_t)(p & 0xff);
}

// ---------------- embeddings (write bf16 states) ----------------
__global__ __launch_bounds__(256) void k_embed_place(
    const float* __restrict__ pf, const float* __restrict__ Wpe,
    const float* __restrict__ bpe, ushort_t* __restrict__ out, int P)
{
    int idx = blockIdx.x*256 + threadIdx.x;     // 4-elem group index over P*32
    if (idx >= P*32) return;
    int p = idx >> 5, q = (idx & 31) << 2;
    float v = pf[p];
    float4 w = *(const float4*)(Wpe + q);
    float4 b = *(const float4*)(bpe + q);
    ushort4 o;
    o.x = f2bf(v*w.x + b.x); o.y = f2bf(v*w.y + b.y);
    o.z = f2bf(v*w.z + b.z); o.w = f2bf(v*w.w + b.w);
    *(ushort4*)(out + (size_t)p*H + q) = o;
}

__global__ __launch_bounds__(256) void k_embed_trans(
    const float* __restrict__ tf, const float* __restrict__ Wte,
    const float* __restrict__ bte, ushort_t* __restrict__ out, int T)
{
    __shared__ float Wl[8*H];
    __shared__ float Bl[H];
    int tid = threadIdx.x;
    #pragma unroll
    for (int t = 0; t < 4; t++) Wl[tid + t*256] = Wte[tid + t*256];
    if (tid < H) Bl[tid] = bte[tid];
    __syncthreads();
    int idx = blockIdx.x*256 + tid;
    if (idx >= T*32) return;
    int t = idx >> 5, q = (idx & 31) << 2;
    float4 acc = *(float4*)(&Bl[q]);
    #pragma unroll
    for (int k = 0; k < 8; k++){
        float s = tf[(size_t)t*8 + k];
        float4 w = *(float4*)(&Wl[k*H + q]);
        acc.x += s*w.x; acc.y += s*w.y; acc.z += s*w.z; acc.w += s*w.w;
    }
    ushort4 o;
    o.x = f2bf(acc.x); o.y = f2bf(acc.y); o.z = f2bf(acc.z); o.w = f2bf(acc.w);
    *(ushort4*)(out + (size_t)t*H + q) = o;
}

// prefix embedding + zero small accumulators + all softmax slots
__global__ void k_init_small(const float* __restrict__ pe, int plen,
                             const float* __restrict__ Wpr, const float* __restrict__ bpr,
                             float* __restrict__ prefix, float* __restrict__ meanP,
                             float* __restrict__ meanT, float* __restrict__ slots)
{
    int c = threadIdx.x;  // 128 threads
    float a = bpr[c];
    for (int k = 0; k < plen; k++) a += pe[k]*Wpr[k*H + c];
    prefix[c] = a;
    meanP[c] = 0.f;
    meanT[c] = 0.f;
    if (c < 16) slots[c] = 0.f;   // fkey-space 0 == -inf; Sp slots start at 0
}

// ---------------- weight transpose + bf16 convert ----------------
// per layer l: WT layout [p2tT 128x128][t2pT 128x128][tuT 128x256][puT 128x256]
__global__ __launch_bounds__(256) void k_wconv(
    const float* __restrict__ p2t_W, const float* __restrict__ t2p_W,
    const float* __restrict__ tu_W,  const float* __restrict__ pu_W,
    ushort_t* __restrict__ WT, int total)
{
    int e = blockIdx.x*256 + threadIdx.x;
    if (e >= total) return;
    int l = e / 98304, o = e - l*98304;
    const float* src; int K, oo;
    if (o < 16384)      { src = p2t_W + (size_t)l*16384; K = 128; oo = o; }
    else if (o < 32768) { src = t2p_W + (size_t)l*16384; K = 128; oo = o - 16384; }
    else if (o < 65536) { src = tu_W  + (size_t)l*32768; K = 256; oo = o - 32768; }
    else                { src = pu_W  + (size_t)l*32768; K = 256; oo = o - 65536; }
    int n = oo / K, k = oo - n*K;
    WT[e] = f2bf(src[(size_t)k*H + n]);
}

// ---------------- CSR build ----------------
__global__ __launch_bounds__(256) void k_zero_ints(int* __restrict__ p, int n)
{
    int i = blockIdx.x*256 + threadIdx.x;
    int stride = gridDim.x*256;
    for (; i < n; i += stride) p[i] = 0;
}

// dst histograms + per-edge segment ranks (2 atomics/edge)
__global__ __launch_bounds__(256) void k_hist2(
    const int* __restrict__ preD, const int* __restrict__ postD, int E,
    int* __restrict__ cntPre, int* __restrict__ cntPost,
    int* __restrict__ rankPre, int* __restrict__ rankPost)
{
    int i = blockIdx.x*256 + threadIdx.x;
    int stride = gridDim.x*256;
    for (; i < E; i += stride){
        rankPre[i] = atomicAdd(&cntPre[preD[i]], 1);
        rankPost[i] = atomicAdd(&cntPost[postD[i]], 1);
    }
}

// ---- multi-block exclusive scan (chunk = 1024 per block) ----
__global__ __launch_bounds__(256) void k_scan_part(
    const int* __restrict__ cnt, int N, int* __restrict__ bsum)
{
    __shared__ int wsum[4];
    int tid = threadIdx.x, lane = tid & 63, wid = tid >> 6;
    int base = blockIdx.x*1024 + tid*4;
    int4 v = make_int4(0,0,0,0);
    if (base + 3 < N) v = *(const int4*)(cnt + base);
    else {
        if (base+0 < N) v.x = cnt[base+0];
        if (base+1 < N) v.y = cnt[base+1];
        if (base+2 < N) v.z = cnt[base+2];
    }
    int s = v.x + v.y + v.z + v.w;
    #pragma unroll
    for (int o = 1; o < 64; o <<= 1) s += __shfl_xor(s, o);
    if (lane == 0) wsum[wid] = s;
    __syncthreads();
    if (tid == 0) bsum[blockIdx.x] = wsum[0] + wsum[1] + wsum[2] + wsum[3];
}

__global__ __launch_bounds__(256) void k_scan_bsum(int* __restrict__ bsum, int nb)
{
    __shared__ int wsum[4];
    int tid = threadIdx.x, lane = tid & 63, wid = tid >> 6;
    int x = (tid < nb) ? bsum[tid] : 0;
    int inc = x;
    #pragma unroll
    for (int o = 1; o < 64; o <<= 1){
        int u = __shfl_up(inc, o);
        if (lane >= o) inc += u;
    }
    if (lane == 63) wsum[wid] = inc;
    __syncthreads();
    int woff = 0;
    if (wid > 0) woff += wsum[0];
    if (wid > 1) woff += wsum[1];
    if (wid > 2) woff += wsum[2];
    if (tid < nb) bsum[tid] = woff + inc - x;
}

__global__ __launch_bounds__(256) void k_scan_final(
    const int* __restrict__ cnt, int N, const int* __restrict__ bsum,
    int* __restrict__ rp, int E)
{
    __shared__ int wsum[4];
    int tid = threadIdx.x, lane = tid & 63, wid = tid >> 6;
    int base = blockIdx.x*1024 + tid*4;
    int4 v = make_int4(0,0,0,0);
    if (base + 3 < N) v = *(const int4*)(cnt + base);
    else {
        if (base+0 < N) v.x = cnt[base+0];
        if (base+1 < N) v.y = cnt[base+1];
        if (base+2 < N) v.z = cnt[base+2];
    }
    int t0 = v.x, t1 = t0 + v.y, t2 = t1 + v.z, t3 = t2 + v.w;
    int inc = t3;
    #pragma unroll
    for (int o = 1; o < 64; o <<= 1){
        int u = __shfl_up(inc, o);
        if (lane >= o) inc += u;
    }
    if (lane == 63) wsum[wid] = inc;
    __syncthreads();
    int woff = 0;
    if (wid > 0) woff += wsum[0];
    if (wid > 1) woff += wsum[1];
    if (wid > 2) woff += wsum[2];
    int off = bsum[blockIdx.x] + woff + inc - t3;
    if (base+0 < N) rp[base+0] = off;
    if (base+1 < N) rp[base+1] = off + t0;
    if (base+2 < N) rp[base+2] = off + t1;
    if (base+3 < N) rp[base+3] = off + t2;
    if (blockIdx.x == 0 && tid == 0) rp[N] = E;
}

// atomic-free CSR fill using precomputed ranks
__global__ __launch_bounds__(256) void k_fill2(
    const int* __restrict__ preS, const int* __restrict__ preD,
    const int* __restrict__ postS, const int* __restrict__ postD, int E,
    const int* __restrict__ rpPre, const int* __restrict__ rankPre, int* __restrict__ csrPre,
    const int* __restrict__ rpPost, const int* __restrict__ rankPost, int* __restrict__ csrPost)
{
    int i = blockIdx.x*256 + threadIdx.x;
    int stride = gridDim.x*256;
    for (; i < E; i += stride){
        csrPre[rpPre[preD[i]] + rankPre[i]] = preS[i];
        csrPost[rpPost[postD[i]] + rankPost[i]] = postS[i];
    }
}

// ---------------- message GEMM: out(fp8) = A @ W + b, partial score (K=128) --
// W strips in REGISTERS (zero LDS). Block = 4 waves = 4 x 32-col strips =
// full 128-col rows per block. Barrier-free. Per-wave score partials -> y4.
__global__ __launch_bounds__(256, 4) void k_gemm_msg(
    const ushort_t* __restrict__ A, const ushort_t* __restrict__ WT,
    const float* __restrict__ bias, uchar_t* __restrict__ out, int M,
    const float* __restrict__ aw, float* __restrict__ y4)
{
    int tid = threadIdx.x;
    int lane = tid & 63, wid = tid >> 6;
    int quad = lane >> 4, l15 = lane & 15;
    int strip = wid*32;
    short8 bfr[2][4];
    float bcol[2], awc[2];
    #pragma unroll
    for (int j = 0; j < 2; j++){
        int col = strip + j*16 + l15;
        #pragma unroll
        for (int kk = 0; kk < 4; kk++)
            bfr[j][kk] = *(const short8*)(WT + (size_t)col*128 + kk*32 + quad*8);
        bcol[j] = bias[col];
        awc[j]  = aw[col];
    }
    int tiles = (M + 15) >> 4;
    for (int t = blockIdx.x; t < tiles; t += gridDim.x){
        int row0 = t << 4;
        int rA = row0 + l15; if (rA >= M) rA = M - 1;
        short8 afr[4];
        #pragma unroll
        for (int kk = 0; kk < 4; kk++)
            afr[kk] = *(const short8*)(A + (size_t)rA*H + kk*32 + quad*8);
        floatx4 acc[2];
        acc[0] = (floatx4)0.f; acc[1] = (floatx4)0.f;
        #pragma unroll
        for (int j = 0; j < 2; j++)
            #pragma unroll
            for (int kk = 0; kk < 4; kk++)
                acc[j] = __builtin_amdgcn_mfma_f32_16x16x32_bf16(afr[kk], bfr[j][kk], acc[j], 0,0,0);
        float pr[4] = {0.f,0.f,0.f,0.f};
        #pragma unroll
        for (int j = 0; j < 2; j++){
            int col = strip + j*16 + l15;
            #pragma unroll
            for (int rr = 0; rr < 4; rr++){
                int grow = row0 + quad*4 + rr;
                if (grow < M){
                    float v = acc[j][rr] + bcol[j];
                    out[(size_t)grow*H + col] = f2fp8(v);
                    pr[rr] += v * awc[j];
                }
            }
        }
        #pragma unroll
        for (int rr = 0; rr < 4; rr++){
            float p = pr[rr];
            p += __shfl_xor(p, 1); p += __shfl_xor(p, 2);
            p += __shfl_xor(p, 4); p += __shfl_xor(p, 8);
            int grow = row0 + quad*4 + rr;
            if (l15 == 0 && grow < M) y4[(size_t)grow*4 + wid] = p;
        }
    }
}

// ---------------- finalize scores: y = sum(y4) + ab; node max -> Mkey --------
__global__ __launch_bounds__(256) void k_scoremax(
    const float* __restrict__ y4, int N, const float* __restrict__ abp,
    float* __restrict__ y, unsigned* __restrict__ Mkey)
{
    __shared__ float wm[4];
    int tid = threadIdx.x;
    int lane = tid & 63, wid = tid >> 6;
    int gid = blockIdx.x*256 + tid, stride = gridDim.x*256;
    float ab = abp[0];
    float lmax = -3.402823466e38f;
    for (int r = gid; r < N; r += stride){
        float4 v = *(const float4*)(y4 + (size_t)r*4);
        float s = v.x + v.y + v.z + v.w + ab;
        y[r] = s;
        lmax = fmaxf(lmax, s);
    }
    #pragma unroll
    for (int o = 1; o < 64; o <<= 1) lmax = fmaxf(lmax, __shfl_xor(lmax, o));
    if (lane == 0) wm[wid] = lmax;
    __syncthreads();
    if (tid == 0){
        float m = fmaxf(fmaxf(wm[0], wm[1]), fmaxf(wm[2], wm[3]));
        atomicMax(Mkey, fkey(m));
    }
}

// ---------------- softmax denominator over edge src list --------------------
// S = sum_e exp(y[src[e]] - M); coalesced src reads, y is L2-resident.
__global__ __launch_bounds__(256) void k_sumexp(
    const int* __restrict__ src, int E, const float* __restrict__ y,
    const unsigned* __restrict__ Mkey, float* __restrict__ Sp)
{
    __shared__ float red[4];
    int tid = threadIdx.x, lane = tid & 63, wid = tid >> 6;
    int gid = blockIdx.x*256 + tid, stride = gridDim.x*256;
    float Mv = funkey(Mkey[0]);
    float ls = 0.f;
    for (int e = gid; e < E; e += stride) ls += expf(y[src[e]] - Mv);
    #pragma unroll
    for (int o = 1; o < 64; o <<= 1) ls += __shfl_xor(ls, o);
    if (lane == 0) red[wid] = ls;
    __syncthreads();
    if (tid == 0) atomicAdd(Sp, red[0] + red[1] + red[2] + red[3]);
}

// ---------------- update GEMM: out = relu(A1 + A1@W_up + invS*(Mb@W_low) + b)
// W strips in REGISTERS, zero-LDS main loop, full 128-col rows per block.
__global__ __launch_bounds__(256, 3) void k_gemm_up(
    const ushort_t* __restrict__ A1, const ushort_t* __restrict__ A2,
    const ushort_t* __restrict__ WT, const float* __restrict__ bias,
    const float* __restrict__ Sp, ushort_t* __restrict__ out, int M,
    float* __restrict__ colsum)
{
    __shared__ float csum[H];
    int tid = threadIdx.x;
    int lane = tid & 63, wid = tid >> 6;
    int quad = lane >> 4, l15 = lane & 15;
    int strip = wid*32;
    short8 bfr[2][8];
    float bcol[2];
    #pragma unroll
    for (int j = 0; j < 2; j++){
        int col = strip + j*16 + l15;
        #pragma unroll
        for (int kk = 0; kk < 8; kk++)
            bfr[j][kk] = *(const short8*)(WT + (size_t)col*256 + kk*32 + quad*8);
        bcol[j] = bias[col];
    }
    float invS = 1.f / Sp[0];
    const bool has_cs = (colsum != nullptr);
    if (has_cs && tid < H) csum[tid] = 0.f;
    float cs[2] = {0.f, 0.f};
    int tiles = (M + 15) >> 4;
    for (int t = blockIdx.x; t < tiles; t += gridDim.x){
        int row0 = t << 4;
        int rA = row0 + l15; if (rA >= M) rA = M - 1;
        short8 afr[8];
        #pragma unroll
        for (int kk = 0; kk < 4; kk++)
            afr[kk] = *(const short8*)(A1 + (size_t)rA*H + kk*32 + quad*8);
        #pragma unroll
        for (int kk = 0; kk < 4; kk++)
            afr[4+kk] = *(const short8*)(A2 + (size_t)rA*H + kk*32 + quad*8);
        floatx4 acc1[2], acc2[2];
        acc1[0] = (floatx4)0.f; acc1[1] = (floatx4)0.f;
        acc2[0] = (floatx4)0.f; acc2[1] = (floatx4)0.f;
        #pragma unroll
        for (int j = 0; j < 2; j++){
            #pragma unroll
            for (int kk = 0; kk < 4; kk++)
                acc1[j] = __builtin_amdgcn_mfma_f32_16x16x32_bf16(afr[kk], bfr[j][kk], acc1[j], 0,0,0);
            #pragma unroll
            for (int kk = 4; kk < 8; kk++)
                acc2[j] = __builtin_amdgcn_mfma_f32_16x16x32_bf16(afr[kk], bfr[j][kk], acc2[j], 0,0,0);
        }
        #pragma unroll
        for (int j = 0; j < 2; j++){
            int col = strip + j*16 + l15;
            #pragma unroll
            for (int rr = 0; rr < 4; rr++){
                int grow = row0 + quad*4 + rr;
                if (grow < M){
                    float v = acc1[j][rr] + invS*acc2[j][rr] + bcol[j]
                            + bf2f(A1[(size_t)grow*H + col]);
                    v = fmaxf(v, 0.f);
                    out[(size_t)grow*H + col] = f2bf(v);
                    if (has_cs) cs[j] += v;
                }
            }
        }
    }
    if (has_cs){
        #pragma unroll
        for (int j = 0; j < 2; j++){
            float v = cs[j];
            v += __shfl_xor(v, 16); v += __shfl_xor(v, 32);
            if (quad == 0) atomicAdd(&csum[strip + j*16 + l15], v);
        }
        __syncthreads();
        if (tid < H) atomicAdd(&colsum[tid], csum[tid]);
    }
}

// accumulate 8 fp8 (one int2) into 8 fp32 with weight
__device__ __forceinline__ void acc8f8(float* a, int2 u, float w){
    floatx2 p;
    p = __builtin_amdgcn_cvt_pk_f32_fp8(u.x, false); a[0] += w*p.x; a[1] += w*p.y;
    p = __builtin_amdgcn_cvt_pk_f32_fp8(u.x, true);  a[2] += w*p.x; a[3] += w*p.y;
    p = __builtin_amdgcn_cvt_pk_f32_fp8(u.y, false); a[4] += w*p.x; a[5] += w*p.y;
    p = __builtin_amdgcn_cvt_pk_f32_fp8(u.y, true);  a[6] += w*p.x; a[7] += w*p.y;
}

// ---------------- CSR gather: fp8 X rows -> UNNORMALIZED bf16 Mb -------------
// Barrier-free, early-return (no block-wide tail sync; skewed degrees retire
// independently). Normalization (1/S) happens in k_gemm_up.
__global__ __launch_bounds__(256) void k_gather(
    const int* __restrict__ rp, const int* __restrict__ csr, int Nrow,
    const float* __restrict__ y, const uchar_t* __restrict__ X,
    ushort_t* __restrict__ Mb, const unsigned* __restrict__ Mkey)
{
    int tid = threadIdx.x;
    int g = tid >> 4, gl = tid & 15;          // 16 groups x 16 lanes
    int r = blockIdx.x*16 + g;
    if (r >= Nrow) return;
    float Mv = funkey(Mkey[0]);
    int j0 = rp[r], j1 = rp[r+1];
    const int2* X8 = (const int2*)X;          // fp8 row = 16 int2 (128 fp8)
    float a[8] = {0.f,0.f,0.f,0.f,0.f,0.f,0.f,0.f};
    int j = j0;
    for (; j + 1 < j1; j += 2){
        int s0 = csr[j], s1 = csr[j+1];
        float e0 = expf(y[s0] - Mv);
        float e1 = expf(y[s1] - Mv);
        int2 u0 = X8[(size_t)s0*16 + gl];
        int2 u1 = X8[(size_t)s1*16 + gl];
        acc8f8(a, u0, e0);
        acc8f8(a, u1, e1);
    }
    if (j < j1){
        int s0 = csr[j];
        float e0 = expf(y[s0] - Mv);
        int2 u0 = X8[(size_t)s0*16 + gl];
        acc8f8(a, u0, e0);
    }
    int4 o;
    o.x = (int)((((unsigned)f2bf(a[1])) << 16) | (unsigned)f2bf(a[0]));
    o.y = (int)((((unsigned)f2bf(a[3])) << 16) | (unsigned)f2bf(a[2]));
    o.z = (int)((((unsigned)f2bf(a[5])) << 16) | (unsigned)f2bf(a[4]));
    o.w = (int)((((unsigned)f2bf(a[7])) << 16) | (unsigned)f2bf(a[6]));
    ((int4*)Mb)[(size_t)r*16 + gl] = o;
}

// ---------------- tiny MLP head ----------------
__global__ __launch_bounds__(256) void k_head(
    const float* __restrict__ meanP, const float* __restrict__ meanT,
    float invP, float invT,
    const float* __restrict__ Wpp, const float* __restrict__ bpp,
    const float* __restrict__ Wtp, const float* __restrict__ btp,
    const float* __restrict__ prefix,
    const float* __restrict__ W1, const float* __restrict__ b1,
    const float* __restrict__ W2, const float* __restrict__ b2,
    float* __restrict__ h2g)
{
    __shared__ float comb[384];
    __shared__ float h1s[256];
    int tid = threadIdx.x;
    if (tid < 128){
        float a = bpp[tid];
        for (int k = 0; k < 128; k++) a += meanP[k]*invP*Wpp[k*H + tid];
        comb[tid] = a;
        comb[256 + tid] = prefix[tid];
    } else {
        int c = tid - 128;
        float a = btp[c];
        for (int k = 0; k < 128; k++) a += meanT[k]*invT*Wtp[k*H + c];
        comb[128 + c] = a;
    }
    __syncthreads();
    {
        float a = b1[tid];
        for (int k = 0; k < 384; k++) a += comb[k]*W1[k*256 + tid];
        h1s[tid] = fmaxf(a, 0.f);
    }
    __syncthreads();
    if (tid < 128){
        float a = b2[tid];
        for (int k = 0; k < 256; k++) a += h1s[k]*W2[k*H + tid];
        h2g[tid] = fmaxf(a, 0.f);
    }
}

// ---------------- logits + sigmoid ----------------
__global__ __launch_bounds__(256) void k_logits(
    const float* __restrict__ h2g, const float* __restrict__ W3,
    const float* __restrict__ b3, float* __restrict__ out, int T)
{
    __shared__ float h2l[128];
    int tid = threadIdx.x;
    if (tid < 128) h2l[tid] = h2g[tid];
    __syncthreads();
    int t = blockIdx.x*256 + tid;
    if (t >= T) return;
    float a = b3[t];
    #pragma unroll 8
    for (int k = 0; k < 128; k++) a += h2l[k]*W3[(size_t)k*T + t];
    out[t] = 1.f/(1.f + expf(-a));
}

// ---------------- launch ----------------
extern "C" void kernel_launch(void* const* d_in, const int* in_sizes, int n_in,
                              void* d_out, int out_size, void* d_ws, size_t ws_size,
                              hipStream_t stream)
{
    (void)n_in; (void)out_size; (void)ws_size;
    const float* pf    = (const float*)d_in[0];
    const float* tf    = (const float*)d_in[1];
    const float* pe    = (const float*)d_in[2];
    const int*   pre   = (const int*)d_in[3];
    const int*   post  = (const int*)d_in[4];
    const float* W_pe  = (const float*)d_in[5];
    const float* b_pe  = (const float*)d_in[6];
    const float* W_te  = (const float*)d_in[7];
    const float* b_te  = (const float*)d_in[8];
    const float* W_pr  = (const float*)d_in[9];
    const float* b_pr  = (const float*)d_in[10];
    const float* p2t_W = (const float*)d_in[11];
    const float* p2t_b = (const float*)d_in[12];
    const float* t2p_W = (const float*)d_in[13];
    const float* t2p_b = (const float*)d_in[14];
    const float* pu_W  = (const float*)d_in[15];
    const float* pu_b  = (const float*)d_in[16];
    const float* tu_W  = (const float*)d_in[17];
    const float* tu_b  = (const float*)d_in[18];
    const float* pa_W  = (const float*)d_in[19];
    const float* pa_b  = (const float*)d_in[20];
    const float* ta_W  = (const float*)d_in[21];
    const float* ta_b  = (const float*)d_in[22];
    const float* W_pp  = (const float*)d_in[23];
    const float* b_pp  = (const float*)d_in[24];
    const float* W_tp  = (const float*)d_in[25];
    const float* b_tp  = (const float*)d_in[26];
    const float* W1    = (const float*)d_in[27];
    const float* b1    = (const float*)d_in[28];
    const float* W2    = (const float*)d_in[29];
    const float* b2    = (const float*)d_in[30];
    const float* W3    = (const float*)d_in[31];
    const float* b3    = (const float*)d_in[32];

    int P = in_sizes[0];
    int T = in_sizes[1] / 8;
    int E = in_sizes[3] / 2;
    int plen = in_sizes[2];
    int L = in_sizes[11] / (H*H);

    float* ws = (float*)d_ws;
    size_t fP = (size_t)P*H, fT = (size_t)T*H;
    size_t fN = (fP > fT) ? fP : fT;
    int   Nmax = (P > T) ? P : T;

    float* yb = ws;                       // [Nmax] fp32 scores
    float* y4 = yb + Nmax;                // [Nmax*4] per-wave score partials
    float* sc = y4 + (size_t)Nmax*4;      // 16 softmax slots + small vectors
    float* meanP   = sc + 16;
    float* meanT   = sc + 144;
    float* prefix  = sc + 272;
    float* h2g     = sc + 400;            // end at sc+544 (16B aligned)

    ushort_t* bh = (ushort_t*)(sc + 544);
    ushort_t* place_h = bh;               // [P,128] bf16
    ushort_t* trans_h = place_h + fP;     // [T,128]
    ushort_t* Mb      = trans_h + fT;     // [Nmax,128] bf16 messages (unnormalized)
    ushort_t* Pb2     = Mb + fN;          // [P,128] ping-pong place
    ushort_t* Tb2     = Pb2 + fP;         // [T,128] ping-pong trans
    ushort_t* WTb     = Tb2 + fT;         // L*98304 bf16 transposed weights
    uchar_t*  Xf8     = (uchar_t*)(WTb + (size_t)L*98304);  // [Nmax,128] fp8 X

    int* iw = (int*)(Xf8 + fN);
    int* cntPre  = iw;                 // [T]
    int* cntPost = cntPre + T;         // [P]
    int* rpPre   = cntPost + P;        // [T+1]
    int* rpPost  = rpPre + (T + 1);    // [P+1]
    int* csrPre  = rpPost + (P + 2);   // [E]
    int* csrPost = csrPre + E;         // [E]
    int* rankPre = csrPost + E;        // [E]
    int* rankPost= rankPre + E;        // [E]
    int* bsumA   = rankPost + E;       // [256]
    int* bsumB   = bsumA + 256;        // [256]

    const int* pre_src  = pre;          const int* pre_dst  = pre + E;
    const int* post_src = post;         const int* post_dst = post + E;

    int wtot = L*98304;
    int nbT = (T + 1023)/1024, nbP = (P + 1023)/1024;

    k_init_small<<<1, 128, 0, stream>>>(pe, plen, W_pr, b_pr, prefix, meanP, meanT, sc);
    k_wconv<<<(wtot + 255)/256, 256, 0, stream>>>(p2t_W, t2p_W, tu_W, pu_W, WTb, wtot);
    k_zero_ints<<<256, 256, 0, stream>>>(iw, P + T);
    k_hist2<<<2048, 256, 0, stream>>>(pre_dst, post_dst, E,
                                      cntPre, cntPost, rankPre, rankPost);
    k_scan_part<<<nbT, 256, 0, stream>>>(cntPre, T, bsumA);
    k_scan_bsum<<<1, 256, 0, stream>>>(bsumA, nbT);
    k_scan_final<<<nbT, 256, 0, stream>>>(cntPre, T, bsumA, rpPre, E);
    k_scan_part<<<nbP, 256, 0, stream>>>(cntPost, P, bsumB);
    k_scan_bsum<<<1, 256, 0, stream>>>(bsumB, nbP);
    k_scan_final<<<nbP, 256, 0, stream>>>(cntPost, P, bsumB, rpPost, E);
    k_fill2<<<1024, 256, 0, stream>>>(pre_src, pre_dst, post_src, post_dst, E,
                                      rpPre, rankPre, csrPre,
                                      rpPost, rankPost, csrPost);

    k_embed_place<<<(P*32 + 255)/256, 256, 0, stream>>>(pf, W_pe, b_pe, place_h, P);
    k_embed_trans<<<(T*32 + 255)/256, 256, 0, stream>>>(tf, W_te, b_te, trans_h, T);

    ushort_t* curP = place_h; ushort_t* altP = Pb2;
    ushort_t* curT = trans_h; ushort_t* altT = Tb2;

    for (int l = 0; l < L; l++){
        const ushort_t* WTl  = WTb + (size_t)l*98304;
        const ushort_t* p2tT = WTl;
        const ushort_t* t2pT = WTl + 16384;
        const ushort_t* tuT  = WTl + 32768;
        const ushort_t* puT  = WTl + 65536;
        const float* p2tb = p2t_b + (size_t)l*H;
        const float* t2pb = t2p_b + (size_t)l*H;
        const float* pub  = pu_b  + (size_t)l*H;
        const float* tub  = tu_b  + (size_t)l*H;
        const float* paW  = pa_W + (size_t)l*H;   const float* pab = pa_b + l;
        const float* taW  = ta_W + (size_t)l*H;   const float* tab = ta_b + l;
        unsigned* MkA = (unsigned*)(sc + l*4 + 0);   float* SpA = sc + l*4 + 1;
        unsigned* MkB = (unsigned*)(sc + l*4 + 2);   float* SpB = sc + l*4 + 3;
        int last = (l == L-1);

        // phase A: place -> transition (partial scores fused)
        k_gemm_msg<<<1024, 256, 0, stream>>>(curP, p2tT, p2tb, Xf8, P, taW, y4);
        k_scoremax<<<128, 256, 0, stream>>>(y4, P, tab, yb, MkA);
        k_sumexp<<<256, 256, 0, stream>>>(pre_src, E, yb, MkA, SpA);
        k_gather<<<(T + 15)/16, 256, 0, stream>>>(rpPre, csrPre, T, yb, Xf8, Mb, MkA);

        // phase B: transform from OLD trans_h (+ its scores)
        k_gemm_msg<<<1024, 256, 0, stream>>>(curT, t2pT, t2pb, Xf8, T, paW, y4);
        k_scoremax<<<128, 256, 0, stream>>>(y4, T, pab, yb, MkB);
        k_sumexp<<<256, 256, 0, stream>>>(post_src, E, yb, MkB, SpB);

        // transition update (consumes Mb = trans_msg, normalized by 1/SpA)
        k_gemm_up<<<1024, 256, 0, stream>>>(curT, Mb, tuT, tub, SpA, altT, T,
                                            last ? meanT : nullptr);

        // place messages, then place update (normalized by 1/SpB)
        k_gather<<<(P + 15)/16, 256, 0, stream>>>(rpPost, csrPost, P, yb, Xf8, Mb, MkB);
        k_gemm_up<<<1024, 256, 0, stream>>>(curP, Mb, puT, pub, SpB, altP, P,
                                            last ? meanP : nullptr);

        ushort_t* tmp;
        tmp = curT; curT = altT; altT = tmp;
        tmp = curP; curP = altP; altP = tmp;
    }

    k_head<<<1, 256, 0, stream>>>(meanP, meanT, 1.f/(float)P, 1.f/(float)T,
                                  W_pp, b_pp, W_tp, b_tp, prefix, W1, b1, W2, b2, h2g);
    k_logits<<<(T + 255)/256, 256, 0, stream>>>(h2g, W3, b3, (float*)d_out, T);
}